// Round 2
// baseline (295.133 us; speedup 1.0000x reference)
//
#include <hip/hip_runtime.h>
#include <math.h>

#define Mq 40000
#define Ns 40000
#define Hh 16
#define Cc 128
#define Kk 15

// ---------------------------------------------------------------------------
// Kernel 1: q_feats = s_feats@Wq + bq ; k_feats = s_feats@Wk + bk  (fused)
// block = 256 threads, 32 rows per block. Thread tile: 8 rows x 4 cols.
// ---------------------------------------------------------------------------
__global__ __launch_bounds__(256) void qk_gemm(
    const float* __restrict__ s_feats,
    const float* __restrict__ Wq, const float* __restrict__ bq,
    const float* __restrict__ Wk, const float* __restrict__ bk,
    float* __restrict__ q_feats, float* __restrict__ k_feats)
{
    __shared__ __align__(16) float ftile[8][32];    // [cc][row]
    __shared__ __align__(16) float wtile[8][256];   // [cc][col (q|k)]
    const int tid  = threadIdx.x;
    const int tx   = tid & 63;
    const int ty   = tid >> 6;
    const int row0 = blockIdx.x * 32;
    const int r0   = ty * 8;
    const bool isK = (tx >= 32);
    const int colq = (tx & 31) * 4;                 // column within 128
    const float* __restrict__ bias = isK ? bk : bq;

    float acc[8][4];
    {
        const float b0 = bias[colq+0], b1 = bias[colq+1];
        const float b2_ = bias[colq+2], b3 = bias[colq+3];
        #pragma unroll
        for (int r = 0; r < 8; ++r) {
            acc[r][0] = b0; acc[r][1] = b1; acc[r][2] = b2_; acc[r][3] = b3;
        }
    }

    for (int kc = 0; kc < Cc; kc += 8) {
        __syncthreads();
        {   // feats tile: 32 rows x 8 c, stored transposed [cc][r]
            const int r = tid >> 3, cc = tid & 7;
            ftile[cc][r] = s_feats[(row0 + r) * Cc + kc + cc];
        }
        {   // weight tile: 8 x 256 (cols 0..127 = Wq, 128..255 = Wk), coalesced
            const float* __restrict__ Wsrc = (tid < 128) ? Wq : Wk;
            const int wc = tid & 127;
            #pragma unroll
            for (int i = 0; i < 8; ++i)
                wtile[i][tid] = Wsrc[(kc + i) * Cc + wc];
        }
        __syncthreads();
        #pragma unroll
        for (int cc = 0; cc < 8; ++cc) {
            const float4 w4 = *(const float4*)&wtile[cc][(isK ? 128 : 0) + colq];
            const float4 fa = *(const float4*)&ftile[cc][r0];
            const float4 fb = *(const float4*)&ftile[cc][r0 + 4];
            const float f[8] = {fa.x, fa.y, fa.z, fa.w, fb.x, fb.y, fb.z, fb.w};
            #pragma unroll
            for (int r = 0; r < 8; ++r) {
                acc[r][0] = fmaf(f[r], w4.x, acc[r][0]);
                acc[r][1] = fmaf(f[r], w4.y, acc[r][1]);
                acc[r][2] = fmaf(f[r], w4.z, acc[r][2]);
                acc[r][3] = fmaf(f[r], w4.w, acc[r][3]);
            }
        }
    }
    float* __restrict__ outp = isK ? k_feats : q_feats;
    #pragma unroll
    for (int r = 0; r < 8; ++r) {
        const float4 v = make_float4(acc[r][0], acc[r][1], acc[r][2], acc[r][3]);
        *(float4*)&outp[(row0 + r0 + r) * Cc + colq] = v;
    }
}

// ---------------------------------------------------------------------------
// Kernel 2: fused geometry + KPConv weighting + grouped attention + aggregate.
// block = 256 threads = 2 queries; per query 128 threads own one channel c.
// ---------------------------------------------------------------------------
__global__ __launch_bounds__(256) void kpt_main(
    const float* __restrict__ q_pts, const float* __restrict__ s_pts,
    const float* __restrict__ s_feats, const int* __restrict__ nb,
    const float* __restrict__ kpts, const float* __restrict__ wkp,
    const float* __restrict__ alpha_w1, const float* __restrict__ alpha_w2,
    const float* __restrict__ alpha_b2,
    const float* __restrict__ q_feats, const float* __restrict__ k_feats,
    float* __restrict__ out)
{
    // w1v[c>>2][j*4 + (c&3)] = alpha_w1[c][j]  -> float4 reads along c for fixed j
    __shared__ __align__(16) float w1v[32][64];
    __shared__ float wt[15][128];                 // per-kernel-point weights
    __shared__ float w2s[16][17];
    __shared__ float b2s[16];
    __shared__ float kpl[48];
    __shared__ __align__(16) float a_s[2][16][132];  // leaky(q-k), padded
    __shared__ float t_s[2][16][17];
    __shared__ float sg_s[2][16][17];
    __shared__ int   id_s[2][16];
    __shared__ int   nn_s[2][16];
    __shared__ float in_s[2][16];

    const int tid = threadIdx.x;
    const int qs  = tid >> 7;          // 0/1: which query of the pair
    const int c   = tid & 127;         // channel
    const int m   = blockIdx.x * 2 + qs;

    // ---- stage shared weights ----
    w2s[tid >> 4][tid & 15] = alpha_w2[tid];          // 256 = 16x16
    if (tid < 16) b2s[tid] = alpha_b2[tid];
    if (tid < 45) kpl[tid] = kpts[tid];
    if (tid < 128) {
        #pragma unroll
        for (int j = 0; j < 16; ++j)
            w1v[tid >> 2][j * 4 + (tid & 3)] = alpha_w1[tid * 16 + j];
    } else {
        const int t2 = tid - 128;
        #pragma unroll
        for (int k = 0; k < Kk; ++k)
            wt[k][t2] = wkp[k * Cc + t2];
    }
    const float qf = q_feats[m * Cc + c];
    __syncthreads();

    // ---- geometry: nearest kernel point + influence (16 lanes per query) ----
    if (c < Hh) {
        const int h  = c;
        const int id = nb[m * Hh + h];
        const float px = s_pts[id*3+0] - q_pts[m*3+0];
        const float py = s_pts[id*3+1] - q_pts[m*3+1];
        const float pz = s_pts[id*3+2] - q_pts[m*3+2];
        float best = 1e30f; int bi = 0;
        #pragma unroll
        for (int k = 0; k < Kk; ++k) {
            const float dx = px - kpl[k*3+0];
            const float dy = py - kpl[k*3+1];
            const float dz = pz - kpl[k*3+2];
            const float d = dx*dx + dy*dy + dz*dz;
            if (d < best) { best = d; bi = k; }
        }
        id_s[qs][h] = id;
        nn_s[qs][h] = bi;
        in_s[qs][h] = fmaxf(0.f, 1.f - sqrtf(best) * 0.5f);   // SIGMA=2
    }
    __syncthreads();

    // ---- a = leaky(q - k[idx]) ----
    #pragma unroll
    for (int h = 0; h < Hh; ++h) {
        const int id = id_s[qs][h];
        const float kv = k_feats[id * Cc + c];
        float x = qf - kv;
        x = fmaxf(x, 0.1f * x);          // LeakyReLU(0.1)
        a_s[qs][h][c] = x;
    }
    __syncthreads();

    // ---- first linear (128->16) + leaky: threads = (h-slot, j) ----
    const int j  = c & 15;
    const int hs = c >> 4;               // 0..7
    #pragma unroll
    for (int b = 0; b < 2; ++b) {
        const int h = b * 8 + hs;
        float av = 0.f;
        #pragma unroll 8
        for (int cb = 0; cb < 32; ++cb) {
            const float4 aa = *(const float4*)&a_s[qs][h][cb * 4];
            const float4 ww = *(const float4*)&w1v[cb][j * 4];
            av += aa.x*ww.x + aa.y*ww.y + aa.z*ww.z + aa.w*ww.w;
        }
        av = fmaxf(av, 0.1f * av);
        t_s[qs][h][j] = av;
    }
    __syncthreads();

    // ---- second linear (16->16) + bias + sigmoid ----
    #pragma unroll
    for (int b = 0; b < 2; ++b) {
        const int h = b * 8 + hs;
        float av = b2s[j];
        #pragma unroll
        for (int jp = 0; jp < 16; ++jp)
            av = fmaf(t_s[qs][h][jp], w2s[jp][j], av);
        sg_s[qs][h][j] = 1.f / (1.f + __expf(-av));
    }
    __syncthreads();

    // ---- gather value, apply KP weight * influence * attention, sum over h ----
    float acc = 0.f;
    #pragma unroll
    for (int h = 0; h < Hh; ++h) {
        const int id = id_s[qs][h];
        const float v = s_feats[id * Cc + c];
        const float w = wt[nn_s[qs][h]][c];
        acc = fmaf(v * w, in_s[qs][h] * sg_s[qs][h][j], acc);
    }
    out[m * Cc + c] = acc;
}

extern "C" void kernel_launch(void* const* d_in, const int* in_sizes, int n_in,
                              void* d_out, int out_size, void* d_ws, size_t ws_size,
                              hipStream_t stream) {
    const float* q_pts   = (const float*)d_in[0];
    const float* s_pts   = (const float*)d_in[1];
    const float* s_feats = (const float*)d_in[2];
    const int*   nb      = (const int*)d_in[3];
    const float* kpts    = (const float*)d_in[4];
    const float* wkp     = (const float*)d_in[5];
    const float* Wq      = (const float*)d_in[6];
    const float* bq      = (const float*)d_in[7];
    const float* Wk      = (const float*)d_in[8];
    const float* bk      = (const float*)d_in[9];
    const float* w1      = (const float*)d_in[10];
    const float* w2      = (const float*)d_in[11];
    const float* b2      = (const float*)d_in[12];
    float* outp    = (float*)d_out;
    float* q_feats = (float*)d_ws;                       // 40000*128 f32
    float* k_feats = q_feats + (size_t)Mq * Cc;          // +20.5 MB

    qk_gemm<<<Mq / 32, 256, 0, stream>>>(s_feats, Wq, bq, Wk, bk, q_feats, k_feats);
    kpt_main<<<Mq / 2, 256, 0, stream>>>(q_pts, s_pts, s_feats, nb, kpts, wkp,
                                         w1, w2, b2, q_feats, k_feats, outp);
}